// Round 1
// baseline (877.476 us; speedup 1.0000x reference)
//
#include <hip/hip_runtime.h>
#include <hip/hip_bf16.h>
#include <stdint.h>

// Problem constants: B=8, N=1024, D_MODEL=1024, A=16, DK=DV=64, D_OUT=1024
// out   : [8192][1024] f32   (d_out + 0)
// attn  : [8][16][1024][1024] f32 (d_out + 8M floats)

using bf16   = __bf16;
using bf16x8 = __attribute__((ext_vector_type(8))) __bf16;
using f32x16 = __attribute__((ext_vector_type(16))) float;

__device__ __forceinline__ void gl_lds16(const bf16* g, bf16* l) {
  // async global->LDS, 16B per lane; LDS dest = wave-uniform base + lane*16
  __builtin_amdgcn_global_load_lds(
      (const __attribute__((address_space(1))) void*)g,
      (__attribute__((address_space(3))) void*)l, 16, 0, 0);
}

// ---------------------------------------------------------------------------
// f32 -> bf16 elementwise convert (8M elements, 8/thread)
__global__ __launch_bounds__(256) void cvt_bf16(const float* __restrict__ in,
                                                bf16* __restrict__ out) {
  const size_t i = (size_t)(blockIdx.x * 256 + threadIdx.x) * 8;
  float4 a = *(const float4*)(in + i);
  float4 b = *(const float4*)(in + i + 4);
  bf16x8 o;
  o[0] = (bf16)a.x; o[1] = (bf16)a.y; o[2] = (bf16)a.z; o[3] = (bf16)a.w;
  o[4] = (bf16)b.x; o[5] = (bf16)b.y; o[6] = (bf16)b.z; o[7] = (bf16)b.w;
  *(bf16x8*)(out + i) = o;
}

// ---------------------------------------------------------------------------
// W [1024(k)][1024(n)] f32  ->  Wt [1024(n)][1024(k)] bf16  (LDS tile transpose)
__global__ __launch_bounds__(256) void transpose_w(const float* __restrict__ W,
                                                   bf16* __restrict__ Wt) {
  __shared__ float t[32][33];
  const int bn = blockIdx.x * 32, bk = blockIdx.y * 32;
  const int tx = threadIdx.x & 31, ty = threadIdx.x >> 5;  // 32 x 8
#pragma unroll
  for (int r = ty; r < 32; r += 8) t[r][tx] = W[(size_t)(bk + r) * 1024 + bn + tx];
  __syncthreads();
#pragma unroll
  for (int r = ty; r < 32; r += 8)
    Wt[(size_t)(bn + r) * 1024 + bk + tx] = (bf16)t[tx][r];
}

// ---------------------------------------------------------------------------
// 128x128-tile bf16 GEMM, K=1024: C[m][n] = sum_k A[m][k] * Bt[n][k]
// MODE 0: write bf16 to [b][a][ns][64]   (Q/K head-major; m=b*1024+ns, n=a*64+d)
// MODE 1: write f32  to [m][1024]        (final out)
// MODE 2: write bf16 to [b][a][d][1024]  (V transposed for PV B-operand reads)
template <int MODE>
__global__ __launch_bounds__(256, 2)
void gemm128(const bf16* __restrict__ A, const bf16* __restrict__ Bt,
             void* __restrict__ Cv) {
  __shared__ bf16 As[128 * 32];
  __shared__ bf16 Bs[128 * 32];
  const int tid = threadIdx.x;
  const int wave = tid >> 6, lane = tid & 63;
  const int M0 = blockIdx.x * 128, Np0 = blockIdx.y * 128;
  const int wm = (wave & 1) * 64, wn = (wave >> 1) * 64;
  const int K = 1024;

  f32x16 acc[2][2];
#pragma unroll
  for (int i = 0; i < 2; ++i)
#pragma unroll
    for (int j = 0; j < 2; ++j)
#pragma unroll
      for (int t = 0; t < 16; ++t) acc[i][j][t] = 0.0f;

  // staging: each wave covers 16 rows per 1KB call (4 lanes x 16B per row)
  const bf16* Ap0 = A + (size_t)(M0 + wave * 16 + (lane >> 2)) * K + (lane & 3) * 8;
  const bf16* Ap1 = Ap0 + (size_t)64 * K;
  const bf16* Bp0 = Bt + (size_t)(Np0 + wave * 16 + (lane >> 2)) * K + (lane & 3) * 8;
  const bf16* Bp1 = Bp0 + (size_t)64 * K;
  bf16* lA0 = &As[wave * 512];
  bf16* lA1 = &As[2048 + wave * 512];
  bf16* lB0 = &Bs[wave * 512];
  bf16* lB1 = &Bs[2048 + wave * 512];

  const int aoff = (wm + (lane & 31)) * 32 + (lane >> 5) * 8;
  const int boff = (wn + (lane & 31)) * 32 + (lane >> 5) * 8;

  for (int k0 = 0; k0 < K; k0 += 32) {
    __syncthreads();
    gl_lds16(Ap0 + k0, lA0);
    gl_lds16(Ap1 + k0, lA1);
    gl_lds16(Bp0 + k0, lB0);
    gl_lds16(Bp1 + k0, lB1);
    __syncthreads();
#pragma unroll
    for (int kk = 0; kk < 2; ++kk) {
      bf16x8 a0 = *(const bf16x8*)&As[aoff + kk * 16];
      bf16x8 a1 = *(const bf16x8*)&As[aoff + 1024 + kk * 16];
      bf16x8 b0 = *(const bf16x8*)&Bs[boff + kk * 16];
      bf16x8 b1 = *(const bf16x8*)&Bs[boff + 1024 + kk * 16];
      acc[0][0] = __builtin_amdgcn_mfma_f32_32x32x16_bf16(a0, b0, acc[0][0], 0, 0, 0);
      acc[0][1] = __builtin_amdgcn_mfma_f32_32x32x16_bf16(a0, b1, acc[0][1], 0, 0, 0);
      acc[1][0] = __builtin_amdgcn_mfma_f32_32x32x16_bf16(a1, b0, acc[1][0], 0, 0, 0);
      acc[1][1] = __builtin_amdgcn_mfma_f32_32x32x16_bf16(a1, b1, acc[1][1], 0, 0, 0);
    }
  }

  // C/D layout (32x32): col = lane&31, row = (reg&3) + 8*(reg>>2) + 4*(lane>>5)
#pragma unroll
  for (int mi = 0; mi < 2; ++mi)
#pragma unroll
    for (int ni = 0; ni < 2; ++ni)
#pragma unroll
      for (int r = 0; r < 16; ++r) {
        const int rowc = (r & 3) + 8 * (r >> 2) + 4 * (lane >> 5);
        const int m = M0 + wm + mi * 32 + rowc;
        const int n = Np0 + wn + ni * 32 + (lane & 31);
        const float v = acc[mi][ni][r];
        if (MODE == 1) {
          ((float*)Cv)[(size_t)m * 1024 + n] = v;
        } else {
          const int b = m >> 10, ns = m & 1023, a = n >> 6, d = n & 63;
          if (MODE == 0)
            ((bf16*)Cv)[(((size_t)(b * 16 + a) * 1024 + ns) << 6) + d] = (bf16)v;
          else
            ((bf16*)Cv)[(((size_t)(b * 16 + a) * 64 + d) << 10) + ns] = (bf16)v;
        }
      }
}

// ---------------------------------------------------------------------------
// Fused attention: per (b, head a, 128-row Q tile):
//   loop over 16 key tiles of 64: S = Q.K^T (MFMA, Q-frags in regs),
//   write S f32 -> attn, S bf16 -> LDS, accumulate O += S.V (k-split over wave pairs)
union SmemA {
  struct {
    bf16 Ks[64 * 72];    // K tile  [n][d], row stride 72 (pad: 4-way max conflict)
    bf16 Vts[64 * 72];   // V tile  [d][n_local]
    bf16 Ss[128 * 72];   // S tile  [m][n_local]
  } s;
  float cbuf[2 * 64 * 64];  // final cross-wave O combine
};

__global__ __launch_bounds__(256, 2)
void attn_k(const bf16* __restrict__ Qb, const bf16* __restrict__ Kb,
            const bf16* __restrict__ Vtb, float* __restrict__ attnp,
            bf16* __restrict__ Eb) {
  __shared__ SmemA sm;
  const int tid = threadIdx.x, wave = tid >> 6, lane = tid & 63;
  const int qt = blockIdx.x, a = blockIdx.y, b = blockIdx.z;
  const size_t head = (size_t)(b * 16 + a);
  const bf16* Qh = Qb + (head * 1024 + qt * 128) * 64;
  const bf16* Kh = Kb + head * 1024 * 64;
  const bf16* Vh = Vtb + head * 64 * 1024;
  float* Ah = attnp + (head << 20) + ((size_t)qt * 128) * 1024;

  const int rh = wave & 1;   // S rows half / PV rows half (same bit)
  const int cn = wave >> 1;  // S col half within j-tile
  const int kh = wave >> 1;  // PV reduction split within j-tile
  const int l31 = lane & 31, lh = lane >> 5;

  // Q fragments in registers: rows rh*64 + mi*32 + l31, k = kk*16 + lh*8
  bf16x8 qf[2][4];
#pragma unroll
  for (int mi = 0; mi < 2; ++mi)
#pragma unroll
    for (int kk = 0; kk < 4; ++kk)
      qf[mi][kk] = *(const bf16x8*)(Qh + (size_t)(rh * 64 + mi * 32 + l31) * 64 +
                                    kk * 16 + lh * 8);

  f32x16 o_acc[2][2];  // [mi(row tile)][dt(d tile)]
#pragma unroll
  for (int i = 0; i < 2; ++i)
#pragma unroll
    for (int j = 0; j < 2; ++j)
#pragma unroll
      for (int t = 0; t < 16; ++t) o_acc[i][j][t] = 0.0f;

  const int sr = tid >> 2, sq = tid & 3;  // staging: row, 32B quarter

  for (int j = 0; j < 16; ++j) {
    __syncthreads();  // prev PV done; safe to restage
    {
      const bf16* gk = Kh + (size_t)(j * 64 + sr) * 64 + sq * 16;
      uint4 v0 = ((const uint4*)gk)[0];
      uint4 v1 = ((const uint4*)gk)[1];
      *(uint4*)&sm.s.Ks[sr * 72 + sq * 16] = v0;
      *(uint4*)&sm.s.Ks[sr * 72 + sq * 16 + 8] = v1;
      const bf16* gv = Vh + (size_t)sr * 1024 + j * 64 + sq * 16;
      uint4 w0 = ((const uint4*)gv)[0];
      uint4 w1 = ((const uint4*)gv)[1];
      *(uint4*)&sm.s.Vts[sr * 72 + sq * 16] = w0;
      *(uint4*)&sm.s.Vts[sr * 72 + sq * 16 + 8] = w1;
    }
    __syncthreads();

    // S tile: wave covers rows rh*64..+63, cols cn*32..+31 of this 64-col j-tile
    f32x16 s0, s1;
#pragma unroll
    for (int t = 0; t < 16; ++t) { s0[t] = 0.0f; s1[t] = 0.0f; }
#pragma unroll
    for (int kk = 0; kk < 4; ++kk) {
      bf16x8 bf = *(const bf16x8*)&sm.s.Ks[(cn * 32 + l31) * 72 + kk * 16 + lh * 8];
      s0 = __builtin_amdgcn_mfma_f32_32x32x16_bf16(qf[0][kk], bf, s0, 0, 0, 0);
      s1 = __builtin_amdgcn_mfma_f32_32x32x16_bf16(qf[1][kk], bf, s1, 0, 0, 0);
    }
    // write S: f32 -> global attn (final output), bf16 -> LDS for PV
#pragma unroll
    for (int r = 0; r < 16; ++r) {
      const int rowc = (r & 3) + 8 * (r >> 2) + 4 * lh;
      const int gcol = j * 64 + cn * 32 + l31;
      Ah[(size_t)(rh * 64 + rowc) * 1024 + gcol] = s0[r];
      Ah[(size_t)(rh * 64 + 32 + rowc) * 1024 + gcol] = s1[r];
      sm.s.Ss[(rh * 64 + rowc) * 72 + cn * 32 + l31] = (bf16)s0[r];
      sm.s.Ss[(rh * 64 + 32 + rowc) * 72 + cn * 32 + l31] = (bf16)s1[r];
    }
    __syncthreads();

    // PV: wave handles O rows rh*64..+63, reduction slice kh*32..+31 of j-tile
#pragma unroll
    for (int kk2 = 0; kk2 < 2; ++kk2) {
      const int nb = kh * 32 + kk2 * 16 + lh * 8;
      bf16x8 sa0 = *(const bf16x8*)&sm.s.Ss[(rh * 64 + l31) * 72 + nb];
      bf16x8 sa1 = *(const bf16x8*)&sm.s.Ss[(rh * 64 + 32 + l31) * 72 + nb];
      bf16x8 vb0 = *(const bf16x8*)&sm.s.Vts[l31 * 72 + nb];
      bf16x8 vb1 = *(const bf16x8*)&sm.s.Vts[(32 + l31) * 72 + nb];
      o_acc[0][0] = __builtin_amdgcn_mfma_f32_32x32x16_bf16(sa0, vb0, o_acc[0][0], 0, 0, 0);
      o_acc[0][1] = __builtin_amdgcn_mfma_f32_32x32x16_bf16(sa0, vb1, o_acc[0][1], 0, 0, 0);
      o_acc[1][0] = __builtin_amdgcn_mfma_f32_32x32x16_bf16(sa1, vb0, o_acc[1][0], 0, 0, 0);
      o_acc[1][1] = __builtin_amdgcn_mfma_f32_32x32x16_bf16(sa1, vb1, o_acc[1][1], 0, 0, 0);
    }
  }

  // combine the two reduction slices (waves w and w+2), write new_emb bf16
  __syncthreads();
  if (wave >= 2) {
#pragma unroll
    for (int mi = 0; mi < 2; ++mi)
#pragma unroll
      for (int dt = 0; dt < 2; ++dt)
#pragma unroll
        for (int r = 0; r < 16; ++r) {
          const int rowc = (r & 3) + 8 * (r >> 2) + 4 * lh;
          sm.cbuf[(wave - 2) * 4096 + (mi * 32 + rowc) * 64 + dt * 32 + l31] =
              o_acc[mi][dt][r];
        }
  }
  __syncthreads();
  if (wave < 2) {
#pragma unroll
    for (int mi = 0; mi < 2; ++mi)
#pragma unroll
      for (int dt = 0; dt < 2; ++dt)
#pragma unroll
        for (int r = 0; r < 16; ++r) {
          const int rowc = (r & 3) + 8 * (r >> 2) + 4 * lh;
          const float v = o_acc[mi][dt][r] +
                          sm.cbuf[wave * 4096 + (mi * 32 + rowc) * 64 + dt * 32 + l31];
          const int grow = qt * 128 + wave * 64 + mi * 32 + rowc;
          Eb[(((size_t)b * 1024 + grow) << 10) + a * 64 + dt * 32 + l31] = (bf16)v;
        }
  }
}

// ---------------------------------------------------------------------------
extern "C" void kernel_launch(void* const* d_in, const int* in_sizes, int n_in,
                              void* d_out, int out_size, void* d_ws, size_t ws_size,
                              hipStream_t stream) {
  (void)in_sizes; (void)n_in; (void)out_size; (void)ws_size;
  const float* query = (const float*)d_in[0];
  const float* key   = (const float*)d_in[1];
  const float* value = (const float*)d_in[2];
  const float* Wq    = (const float*)d_in[3];
  const float* Wk    = (const float*)d_in[4];
  const float* Wv    = (const float*)d_in[5];
  const float* Wo    = (const float*)d_in[6];
  float* out  = (float*)d_out;
  float* attn = out + (size_t)8 * 1024 * 1024;

  char* ws = (char*)d_ws;  // 82 MB of bf16 staging
  bf16* Xb  = (bf16*)(ws);                        // [8192][1024] converted input (reused)
  bf16* Qb  = (bf16*)(ws + ((size_t)16 << 20));   // [8][16][1024][64]
  bf16* Kb  = (bf16*)(ws + ((size_t)32 << 20));   // [8][16][1024][64]
  bf16* Vtb = (bf16*)(ws + ((size_t)48 << 20));   // [8][16][64][1024]
  bf16* Eb  = (bf16*)(ws + ((size_t)64 << 20));   // [8192][1024] new_emb
  bf16* Wt  = (bf16*)(ws + ((size_t)80 << 20));   // [1024][1024] weight^T (reused)

  const dim3 blk(256);
  const dim3 gG(64, 8);     // GEMM: 8192/128 x 1024/128
  const dim3 gT(32, 32);    // transpose tiles
  const dim3 gA(8, 16, 8);  // attention: qtile x head x batch

  // Q path
  cvt_bf16<<<4096, blk, 0, stream>>>(query, Xb);
  transpose_w<<<gT, blk, 0, stream>>>(Wq, Wt);
  gemm128<0><<<gG, blk, 0, stream>>>(Xb, Wt, Qb);
  // K path
  cvt_bf16<<<4096, blk, 0, stream>>>(key, Xb);
  transpose_w<<<gT, blk, 0, stream>>>(Wk, Wt);
  gemm128<0><<<gG, blk, 0, stream>>>(Xb, Wt, Kb);
  // V path (transposed output)
  cvt_bf16<<<4096, blk, 0, stream>>>(value, Xb);
  transpose_w<<<gT, blk, 0, stream>>>(Wv, Wt);
  gemm128<2><<<gG, blk, 0, stream>>>(Xb, Wt, Vtb);
  // fused attention (writes attn f32 + new_emb bf16)
  attn_k<<<gA, blk, 0, stream>>>(Qb, Kb, Vtb, attn, Eb);
  // output projection
  transpose_w<<<gT, blk, 0, stream>>>(Wo, Wt);
  gemm128<1><<<gG, blk, 0, stream>>>(Eb, Wt, out);
}